// Round 9
// baseline (556.240 us; speedup 1.0000x reference)
//
#include <hip/hip_runtime.h>
#include <stdint.h>

typedef unsigned short u16;
typedef __attribute__((ext_vector_type(8))) __bf16 bf16x8;
typedef __attribute__((ext_vector_type(4))) float f32x4;

#define B_TOTAL 65536
#define KPAD1   1440   // 1424 padded to multiple of 32

__device__ __forceinline__ u16 f2bf(float f) {
  union { float f; uint32_t u; } v; v.f = f;
  uint32_t r = v.u + 0x7fffu + ((v.u >> 16) & 1u);
  return (u16)(r >> 16);
}
__device__ __forceinline__ float bf2f(u16 h) {
  union { uint32_t u; float f; } v; v.u = ((uint32_t)h) << 16;
  return v.f;
}

__device__ __forceinline__ void gload16(const void* g, void* lds) {
  __builtin_amdgcn_global_load_lds(
      (const __attribute__((address_space(1))) uint32_t*)g,
      (__attribute__((address_space(3))) uint32_t*)lds, 16, 0, 0);
}

// ---------------- weight prep: f32 [K][N] -> bf16 [N][Kpad] (transposed, zero-padded K)
__global__ void wprep_kernel(const float* __restrict__ W, u16* __restrict__ Wt,
                             int K, int N, int Kpad) {
  int o = blockIdx.x * 256 + threadIdx.x;
  if (o >= N * Kpad) return;
  int k = o % Kpad;
  int n = o / Kpad;
  float v = (k < K) ? W[(size_t)k * N + n] : 0.0f;
  Wt[o] = f2bf(v);
}

// ---------------- gather + concat -> X bf16 [Bc][1440]
struct GatherArgs {
  const int*   idx[15];
  const float* E[15];
  const int*   idx_u;
  const float* E_u;
};

constexpr int FDIM[15] = {128,128,128,16,16,96,144,64,80,64,48,144,96,16,144};
constexpr int FOFF[15] = {0,128,256,384,400,416,512,656,720,800,864,912,1056,1152,1168};

__global__ void gather_kernel(GatherArgs p, u16* __restrict__ X, int row_base) {
  const int lane = threadIdx.x & 63;
  const int row  = blockIdx.x * 4 + (threadIdx.x >> 6);
  const int grow = row_base + row;
  u16* xrow = X + (size_t)row * KPAD1;

#pragma unroll
  for (int f = 0; f < 15; ++f) {
    const int id = p.idx[f][grow];
    const float* src = p.E[f] + (size_t)id * FDIM[f];
    const int ng = FDIM[f] / 4;
    if (lane < ng) {
      const float4 v = *reinterpret_cast<const float4*>(src + lane * 4);
      ushort4 o;
      o.x = f2bf(v.x); o.y = f2bf(v.y); o.z = f2bf(v.z); o.w = f2bf(v.w);
      *reinterpret_cast<ushort4*>(xrow + FOFF[f] + lane * 4) = o;
    }
  }
  // userids mean-pool over 50, dim 112: lanes 0..27 take 4 cols each, 2-deep ILP
  const int* iu = p.idx_u + (size_t)grow * 50;
  if (lane < 28) {
    float4 s0 = {0.f, 0.f, 0.f, 0.f}, s1 = {0.f, 0.f, 0.f, 0.f};
#pragma unroll 5
    for (int j = 0; j < 50; j += 2) {
      const int i0 = iu[j];
      const int i1 = iu[j + 1];
      const float4 v0 = *reinterpret_cast<const float4*>(p.E_u + (size_t)i0 * 112 + lane * 4);
      const float4 v1 = *reinterpret_cast<const float4*>(p.E_u + (size_t)i1 * 112 + lane * 4);
      s0.x += v0.x; s0.y += v0.y; s0.z += v0.z; s0.w += v0.w;
      s1.x += v1.x; s1.y += v1.y; s1.z += v1.z; s1.w += v1.w;
    }
    const float inv = 1.0f / 50.0f;
    ushort4 o;
    o.x = f2bf((s0.x + s1.x) * inv);
    o.y = f2bf((s0.y + s1.y) * inv);
    o.z = f2bf((s0.z + s1.z) * inv);
    o.w = f2bf((s0.w + s1.w) * inv);
    *reinterpret_cast<ushort4*>(xrow + 1312 + lane * 4) = o;
  } else if (lane < 32) {
    ushort4 z; z.x = 0; z.y = 0; z.z = 0; z.w = 0;
    *reinterpret_cast<ushort4*>(xrow + 1424 + (lane - 28) * 4) = z;
  }
}

// ---------------- gemm8: 256x256 tile, BK=32, 4-buffer register-prefetch pipeline
// C[M][N] = relu(A[M][K] * Wt[N][K]^T + bias), bf16 out.
// LDS swizzle (involution): physical 16B-slot = logical_slot ^ ((row>>1)&3).
// Pipeline: regs hold tile t; during tile t issue ds_reads for t+1 (consumed
// next iter -> latency hidden under MFMAs) and stage t+3 (vmcnt(4) counted).
// Safety: lgkmcnt(0) before each barrier => every wave's reads drained before
// any wave can pass and overwrite a buffer; stage issued after the barrier.
#define TILE_ELE 16384   // u16 elems per buffer (A 8192 + B 8192)

template<int K>
__global__ __launch_bounds__(512, 2) void gemm8(
    const u16* __restrict__ A, const u16* __restrict__ Wt,
    const float* __restrict__ bias, u16* __restrict__ C,
    int N, int gm) {
  extern __shared__ __align__(16) u16 lds[];
  constexpr int NT = K / 32;
  const int tid  = threadIdx.x;
  const int w    = tid >> 6;
  const int lane = tid & 63;
  const int fr   = lane & 15;
  const int kg   = lane >> 4;
  const int wm   = w >> 2;      // 0..1
  const int wn   = w & 3;       // 0..3

  // bijective XCD swizzle (m204), M-major so an XCD chunk shares the weight panel
  const int nwg = gridDim.x;
  const int q = nwg >> 3, r = nwg & 7;
  const int xcd = blockIdx.x & 7, lid = blockIdx.x >> 3;
  const int swz = (xcd < r) ? (xcd * (q + 1) + lid) : (r * (q + 1) + (xcd - r) * q + lid);
  const int bm = swz % gm, bn = swz / gm;
  const int rowBase = bm * 256, colBase = bn * 256;

  // staging: thread i = w*64+lane covers LDS bytes i*16 of a 4096-elem half-tile
  // logical slot fetched from global = (lane&3) ^ ((lane>>3)&3)
  const int srow  = lane >> 2;
  const int sslot = (lane & 3) ^ ((lane >> 3) & 3);
  const u16* Asrc0 = A  + (size_t)(rowBase + w * 16 + srow) * K + sslot * 8;
  const u16* Bsrc0 = Wt + (size_t)(colBase + w * 16 + srow) * K + sslot * 8;
  const size_t rstep = (size_t)128 * K;

  f32x4 acc[8][4];
#pragma unroll
  for (int m = 0; m < 8; ++m)
#pragma unroll
    for (int n = 0; n < 4; ++n)
      acc[m][n] = f32x4{0.f, 0.f, 0.f, 0.f};

  // read-side swizzled fragment bases (elems): physical slot = kg ^ ((fr>>1)&3)
  const int aslot8 = (kg ^ ((fr >> 1) & 3)) * 8;
  const int ardA = (wm * 128 + fr) * 32 + aslot8;
  const int ardB = (wn * 64 + fr) * 32 + aslot8 + 8192;

  auto stage = [&](const u16* src0, int ldsElemBase, int kt) {
    const u16* s = src0 + (size_t)kt * 32;
    gload16(s,         &lds[ldsElemBase + w * 512]);
    gload16(s + rstep, &lds[ldsElemBase + w * 512 + 4096]);
  };
  auto READ = [&](bf16x8 (&dst)[12], int bi) {
    const int base = bi * TILE_ELE;
#pragma unroll
    for (int i = 0; i < 4; ++i) {
      dst[i]     = *(const bf16x8*)&lds[base + ardA + i * 512];
      dst[4 + i] = *(const bf16x8*)&lds[base + ardB + i * 512];
      dst[8 + i] = *(const bf16x8*)&lds[base + ardA + 2048 + i * 512];
    }
  };
  auto MFMA = [&](bf16x8 (&cur)[12]) {
    __builtin_amdgcn_s_setprio(1);
#pragma unroll
    for (int n = 0; n < 4; ++n) {
      bf16x8 bf = cur[4 + n];
#pragma unroll
      for (int m = 0; m < 4; ++m) {
        acc[m][n]     = __builtin_amdgcn_mfma_f32_16x16x32_bf16(bf, cur[m],     acc[m][n],     0, 0, 0);
        acc[4 + m][n] = __builtin_amdgcn_mfma_f32_16x16x32_bf16(bf, cur[8 + m], acc[4 + m][n], 0, 0, 0);
      }
    }
    __builtin_amdgcn_s_setprio(0);
  };
  auto BODY = [&](int t, bf16x8 (&cur)[12], bf16x8 (&nxt)[12]) {
    if (t + 1 < NT) {
      // all my ds_reads (incl. cur's) complete before I can pass the barrier:
      // guarantees no wave overwrites a buffer that any wave still reads.
      asm volatile("s_waitcnt lgkmcnt(0)" ::: "memory");
      if (t + 2 < NT) asm volatile("s_waitcnt vmcnt(4)" ::: "memory");
      else            asm volatile("s_waitcnt vmcnt(0)" ::: "memory");
      __builtin_amdgcn_s_barrier();
      if (t + 3 < NT) {
        const int sb = (t + 3) & 3;
        stage(Asrc0, sb * TILE_ELE,        t + 3);
        stage(Bsrc0, sb * TILE_ELE + 8192, t + 3);
      }
      READ(nxt, (t + 1) & 3);   // consumed next iteration -> latency under MFMAs
    }
    MFMA(cur);
  };

  // prologue: stage tiles 0,1,2 (12 VMEM); wait tile 0; preload regs
  stage(Asrc0, 0 * TILE_ELE,        0);
  stage(Bsrc0, 0 * TILE_ELE + 8192, 0);
  stage(Asrc0, 1 * TILE_ELE,        1);
  stage(Bsrc0, 1 * TILE_ELE + 8192, 1);
  stage(Asrc0, 2 * TILE_ELE,        2);
  stage(Bsrc0, 2 * TILE_ELE + 8192, 2);
  asm volatile("s_waitcnt vmcnt(8)" ::: "memory");
  __builtin_amdgcn_s_barrier();

  bf16x8 rA[12], rB[12];
  READ(rA, 0);

  int t = 0;
#pragma unroll 1
  for (; t + 2 <= NT; t += 2) {
    BODY(t,     rA, rB);
    BODY(t + 1, rB, rA);
  }
  if (NT & 1) BODY(NT - 1, rA, rB);

  // epilogue: bias + relu + packed bf16x4 (8B) stores (D^T layout).
#pragma unroll
  for (int mm = 0; mm < 8; ++mm) {
    const int row = rowBase + wm * 128 + (mm >> 2) * 64 + (mm & 3) * 16 + fr;
#pragma unroll
    for (int n = 0; n < 4; ++n) {
      const int col0 = colBase + wn * 64 + n * 16 + kg * 4;
      ushort4 o;
      o.x = f2bf(fmaxf(acc[mm][n][0] + bias[col0 + 0], 0.f));
      o.y = f2bf(fmaxf(acc[mm][n][1] + bias[col0 + 1], 0.f));
      o.z = f2bf(fmaxf(acc[mm][n][2] + bias[col0 + 2], 0.f));
      o.w = f2bf(fmaxf(acc[mm][n][3] + bias[col0 + 3], 0.f));
      *reinterpret_cast<ushort4*>(&C[(size_t)row * N + col0]) = o;
    }
  }
}

// ---------------- final: h3[Bc][256] -> relu(h3*W4+b4) -> softmax(2) -> f32 out
__global__ void final_kernel(const u16* __restrict__ H3, const float* __restrict__ W4,
                             const float* __restrict__ b4, float* __restrict__ out, int M) {
  const int lane = threadIdx.x & 63;
  const int row  = blockIdx.x * 4 + (threadIdx.x >> 6);
  const ushort4 h = *reinterpret_cast<const ushort4*>(H3 + (size_t)row * 256 + lane * 4);
  const float x0 = bf2f(h.x), x1 = bf2f(h.y), x2 = bf2f(h.z), x3 = bf2f(h.w);
  const float2 w0 = *reinterpret_cast<const float2*>(W4 + (size_t)(lane * 4 + 0) * 2);
  const float2 w1 = *reinterpret_cast<const float2*>(W4 + (size_t)(lane * 4 + 1) * 2);
  const float2 w2 = *reinterpret_cast<const float2*>(W4 + (size_t)(lane * 4 + 2) * 2);
  const float2 w3 = *reinterpret_cast<const float2*>(W4 + (size_t)(lane * 4 + 3) * 2);
  float s0 = x0 * w0.x + x1 * w1.x + x2 * w2.x + x3 * w3.x;
  float s1 = x0 * w0.y + x1 * w1.y + x2 * w2.y + x3 * w3.y;
#pragma unroll
  for (int off = 32; off > 0; off >>= 1) {
    s0 += __shfl_xor(s0, off);
    s1 += __shfl_xor(s1, off);
  }
  if (lane == 0) {
    float z0 = fmaxf(s0 + b4[0], 0.f);
    float z1 = fmaxf(s1 + b4[1], 0.f);
    float mx = fmaxf(z0, z1);
    float e0 = __expf(z0 - mx), e1 = __expf(z1 - mx);
    float inv = 1.0f / (e0 + e1);
    out[(size_t)row * 2]     = e0 * inv;
    out[(size_t)row * 2 + 1] = e1 * inv;
  }
}

// ---------------- host side
extern "C" void kernel_launch(void* const* d_in, const int* in_sizes, int n_in,
                              void* d_out, int out_size, void* d_ws, size_t ws_size,
                              hipStream_t stream) {
  const float* W1 = (const float*)d_in[32];
  const float* b1 = (const float*)d_in[33];
  const float* W2 = (const float*)d_in[34];
  const float* b2 = (const float*)d_in[35];
  const float* W3 = (const float*)d_in[36];
  const float* b3 = (const float*)d_in[37];
  const float* W4 = (const float*)d_in[38];
  const float* b4 = (const float*)d_in[39];

  // host-side, non-stream, deterministic on every call
  (void)hipFuncSetAttribute(reinterpret_cast<const void*>(&gemm8<KPAD1>),
                            hipFuncAttributeMaxDynamicSharedMemorySize, 131072);
  (void)hipFuncSetAttribute(reinterpret_cast<const void*>(&gemm8<1024>),
                            hipFuncAttributeMaxDynamicSharedMemorySize, 131072);
  (void)hipFuncSetAttribute(reinterpret_cast<const void*>(&gemm8<512>),
                            hipFuncAttributeMaxDynamicSharedMemorySize, 131072);

  char* ws = (char*)d_ws;
  size_t off = 0;
  auto alloc = [&](size_t bytes) -> void* {
    void* p = ws + off;
    off += (bytes + 255) & ~(size_t)255;
    return p;
  };

  u16* W1t = (u16*)alloc((size_t)1024 * KPAD1 * 2);
  u16* W2t = (u16*)alloc((size_t)512 * 1024 * 2);
  u16* W3t = (u16*)alloc((size_t)256 * 512 * 2);
  const size_t fixed = off;

  int nc = 64;
  const int cands[7] = {1, 2, 4, 8, 16, 32, 64};
  for (int ci = 0; ci < 7; ++ci) {
    size_t Bc = (size_t)B_TOTAL / cands[ci];
    size_t need = fixed + Bc * (KPAD1 + 1024 + 512 + 256) * 2 + 4096;
    if (need <= ws_size) { nc = cands[ci]; break; }
  }
  const int Bc = B_TOTAL / nc;

  u16* X  = (u16*)alloc((size_t)Bc * KPAD1 * 2);
  u16* H1 = (u16*)alloc((size_t)Bc * 1024 * 2);
  u16* H2 = (u16*)alloc((size_t)Bc * 512 * 2);
  u16* H3 = (u16*)alloc((size_t)Bc * 256 * 2);

  wprep_kernel<<<(1024 * KPAD1 + 255) / 256, 256, 0, stream>>>(W1, W1t, 1424, 1024, KPAD1);
  wprep_kernel<<<(512 * 1024 + 255) / 256, 256, 0, stream>>>(W2, W2t, 1024, 512, 1024);
  wprep_kernel<<<(256 * 512 + 255) / 256, 256, 0, stream>>>(W3, W3t, 512, 256, 512);

  GatherArgs ga;
  for (int f = 0; f < 15; ++f) {
    ga.idx[f] = (const int*)d_in[2 * f];
    ga.E[f]   = (const float*)d_in[2 * f + 1];
  }
  ga.idx_u = (const int*)d_in[30];
  ga.E_u   = (const float*)d_in[31];

  const int gm = Bc / 256;
  for (int c = 0; c < nc; ++c) {
    gather_kernel<<<Bc / 4, 256, 0, stream>>>(ga, X, c * Bc);
    gemm8<KPAD1><<<gm * (1024 / 256), 512, 131072, stream>>>(X, W1t, b1, H1, 1024, gm);
    gemm8<1024><<<gm * (512 / 256), 512, 131072, stream>>>(H1, W2t, b2, H2, 512, gm);
    gemm8<512><<<gm * (256 / 256), 512, 131072, stream>>>(H2, W3t, b3, H3, 256, gm);
    final_kernel<<<Bc / 4, 256, 0, stream>>>(H3, W4, b4, (float*)d_out + (size_t)c * Bc * 2, Bc);
  }
}